// Round 3
// baseline (257.169 us; speedup 1.0000x reference)
//
#include <hip/hip_runtime.h>

// RGCN: out = relu( sum_r A_r @ (X W_r) + X Sk + bias )
// N=8192, F=U=64, R=4, B=20.  A (4,8192,8192) fp32 = 1.07 GB -> HBM-bound.
// Main kernel: relation-split blocks (r = blk&3 -> B panel L2-resident per XCD),
// per-wave private A staging + block-shared B staging, depth-4 counted-vmcnt
// pipeline with 2 raw s_barriers per K-step. Cross-relation sum via fp32 atomics.

typedef float v4f __attribute__((ext_vector_type(4)));
typedef unsigned int v4u __attribute__((ext_vector_type(4)));
typedef short v8s __attribute__((ext_vector_type(8)));

__device__ __forceinline__ unsigned short f2bf(float f) {
  // round-to-nearest-even f32 -> bf16
  unsigned int u = __builtin_bit_cast(unsigned int, f);
  return (unsigned short)((u + 0x7fffu + ((u >> 16) & 1u)) >> 16);
}

__device__ __forceinline__ void gload16(const void* g, void* l) {
  __builtin_amdgcn_global_load_lds((const __attribute__((address_space(1))) void*)g,
                                   (__attribute__((address_space(3))) void*)l, 16, 0, 0);
}

// ---------------- kernel 0: W[r][f][u] = sum_k bases[f][u][k] * coef[r][k] ----
__global__ __launch_bounds__(256) void rgcn_wk(const float* __restrict__ bases,
                                               const float* __restrict__ coef,
                                               float* __restrict__ W) {
  int i = blockIdx.x * 256 + threadIdx.x;  // 64*256 = 16384 = R*F*U
  int r = i >> 12;
  int fu = i & 4095;
  float s = 0.f;
#pragma unroll
  for (int k = 0; k < 20; ++k) s += bases[fu * 20 + k] * coef[r * 20 + k];
  W[i] = s;
}

// ---------------- kernel 1: xw (bf16, swizzled to B-fragment layout) + selfout
// xwf layout: for K-step (r, m0=32*mb) and u-tile ut, lane l, elem j holds
//   xw[r][m0 + 8*(l>>4) + j][ut*16 + (l&15)]
//   at index ((r*256 + mb)*4 + ut)*512 + l*8 + j
__global__ __launch_bounds__(256) void rgcn_prep(const float* __restrict__ x,
                                                 const float* __restrict__ W,
                                                 const float* __restrict__ sk,
                                                 const float* __restrict__ bias,
                                                 unsigned short* __restrict__ xwf,
                                                 float* __restrict__ selfout) {
  __shared__ float lx[2048];            // 32 rows x 64 f
  __shared__ unsigned short lxw[8192];  // 4 rel x 2048 swizzled bf16
  const int t = threadIdx.x;
  const int blk = blockIdx.x;
  const int n0 = blk * 32;
  for (int i = t; i < 2048; i += 256) lx[i] = x[(size_t)n0 * 64 + i];
  __syncthreads();
  const int u = t & 63, rq = t >> 6;  // each thread: column u, rows rq*8..rq*8+7
  float acc[8][5];
#pragma unroll
  for (int p = 0; p < 8; ++p)
#pragma unroll
    for (int c = 0; c < 5; ++c) acc[p][c] = 0.f;
  const float* wu = W + u;   // W[r][f][u] = wu[r*4096 + f*64]
  const float* sku = sk + u;
#pragma unroll 4
  for (int f = 0; f < 64; ++f) {
    float w0 = wu[f * 64];
    float w1 = wu[4096 + f * 64];
    float w2 = wu[8192 + f * 64];
    float w3 = wu[12288 + f * 64];
    float w4 = sku[f * 64];
#pragma unroll
    for (int p = 0; p < 8; ++p) {
      float xv = lx[(rq * 8 + p) * 64 + f];
      acc[p][0] += xv * w0;
      acc[p][1] += xv * w1;
      acc[p][2] += xv * w2;
      acc[p][3] += xv * w3;
      acc[p][4] += xv * w4;
    }
  }
  const float bu = bias[u];
#pragma unroll
  for (int p = 0; p < 8; ++p) {
    int km = rq * 8 + p;  // local m index 0..31
    selfout[(size_t)(n0 + km) * 64 + u] = acc[p][4] + bu;
    int idx = (u >> 4) * 512 + ((km >> 3) * 16 + (u & 15)) * 8 + (km & 7);
#pragma unroll
    for (int r = 0; r < 4; ++r) lxw[r * 2048 + idx] = f2bf(acc[p][r]);
  }
  __syncthreads();
  const unsigned int* lsrc = (const unsigned int*)lxw;
  unsigned int* gdst = (unsigned int*)xwf;
  for (int i = t; i < 4096; i += 256) {  // 4 rel x 1024 dwords, coalesced
    int r = i >> 10, q = i & 1023;
    gdst[(size_t)(r * 256 + blk) * 1024 + q] = lsrc[i];
  }
}

// ---------------- kernel 2: out += sum over K of A_r @ xw_r (atomic) --------
// LDS: A: wave w, buf p at (w*4+p)*4096 (32 rows x 8 slots of 16B, slot
//      swizzled c^(row&7)); B (shared): buf p at 65536 + p*4096, linear,
//      frag ut at ut*1024 + l*16.

#define PACK8(S, X0, X1)          \
  {                               \
    S[0] = (short)f2bf(X0.x);     \
    S[1] = (short)f2bf(X0.y);     \
    S[2] = (short)f2bf(X0.z);     \
    S[3] = (short)f2bf(X0.w);     \
    S[4] = (short)f2bf(X1.x);     \
    S[5] = (short)f2bf(X1.y);     \
    S[6] = (short)f2bf(X1.z);     \
    S[7] = (short)f2bf(X1.w);     \
  }

#define STAGE(P)                                          \
  {                                                       \
    char* ab = Aw + (P)*4096;                             \
    gload16(aps0, ab);                                    \
    gload16(aps1, ab + 1024);                             \
    gload16(aps2, ab + 2048);                             \
    gload16(aps3, ab + 3072);                             \
    char* bb = Bb + (P)*4096 + w * 2048;                  \
    gload16(bsrc, bb);                                    \
    gload16(bsrc + 512, bb + 1024);                       \
    aps0 += 32; aps1 += 32; aps2 += 32; aps3 += 32;       \
    bsrc += 2048;                                         \
  }

#define STEP(P, VMN, DO_STAGE)                                             \
  {                                                                        \
    asm volatile("s_waitcnt vmcnt(" #VMN ")" ::: "memory");                \
    __builtin_amdgcn_sched_barrier(0);                                     \
    __builtin_amdgcn_s_barrier();                                          \
    __builtin_amdgcn_sched_barrier(0);                                     \
    const char* ap = Aw + (P)*4096;                                        \
    const char* bp = Bb + (P)*4096;                                        \
    v4f a00 = *(const v4f*)(ap + ao00);                                    \
    v4f a01 = *(const v4f*)(ap + ao01);                                    \
    v4f a10 = *(const v4f*)(ap + ao10);                                    \
    v4f a11 = *(const v4f*)(ap + ao11);                                    \
    v4u b0 = *(const v4u*)(bp + bo);                                       \
    v4u b1 = *(const v4u*)(bp + bo + 1024);                                \
    v4u b2 = *(const v4u*)(bp + bo + 2048);                                \
    v4u b3 = *(const v4u*)(bp + bo + 3072);                                \
    asm volatile("s_waitcnt lgkmcnt(0)" ::: "memory");                     \
    __builtin_amdgcn_sched_barrier(0);                                     \
    __builtin_amdgcn_s_barrier();                                          \
    __builtin_amdgcn_sched_barrier(0);                                     \
    if (DO_STAGE) STAGE(P)                                                 \
    v8s af0, af1;                                                          \
    PACK8(af0, a00, a01);                                                  \
    PACK8(af1, a10, a11);                                                  \
    v8s bf0 = __builtin_bit_cast(v8s, b0);                                 \
    v8s bf1 = __builtin_bit_cast(v8s, b1);                                 \
    v8s bf2 = __builtin_bit_cast(v8s, b2);                                 \
    v8s bf3 = __builtin_bit_cast(v8s, b3);                                 \
    acc00 = __builtin_amdgcn_mfma_f32_16x16x32_bf16(af0, bf0, acc00, 0, 0, 0); \
    acc01 = __builtin_amdgcn_mfma_f32_16x16x32_bf16(af0, bf1, acc01, 0, 0, 0); \
    acc02 = __builtin_amdgcn_mfma_f32_16x16x32_bf16(af0, bf2, acc02, 0, 0, 0); \
    acc03 = __builtin_amdgcn_mfma_f32_16x16x32_bf16(af0, bf3, acc03, 0, 0, 0); \
    acc10 = __builtin_amdgcn_mfma_f32_16x16x32_bf16(af1, bf0, acc10, 0, 0, 0); \
    acc11 = __builtin_amdgcn_mfma_f32_16x16x32_bf16(af1, bf1, acc11, 0, 0, 0); \
    acc12 = __builtin_amdgcn_mfma_f32_16x16x32_bf16(af1, bf2, acc12, 0, 0, 0); \
    acc13 = __builtin_amdgcn_mfma_f32_16x16x32_bf16(af1, bf3, acc13, 0, 0, 0); \
  }

#define ATOM_FRAG(ACC, RF, UT)                                   \
  atomicAdd(ob + ((RF)*16 + 0) * 64 + (UT)*16, ACC.x);           \
  atomicAdd(ob + ((RF)*16 + 1) * 64 + (UT)*16, ACC.y);           \
  atomicAdd(ob + ((RF)*16 + 2) * 64 + (UT)*16, ACC.z);           \
  atomicAdd(ob + ((RF)*16 + 3) * 64 + (UT)*16, ACC.w);

__global__ __launch_bounds__(256, 1) void rgcn_main(const float* __restrict__ A,
                                                    const unsigned short* __restrict__ xwf,
                                                    float* __restrict__ out) {
  __shared__ __align__(16) char smem[81920];  // A: 4w x 4buf x 4KB; B: 4buf x 4KB
  const int tid = threadIdx.x;
  const int r = blockIdx.x & 3;        // same r for all blocks on an XCD
  const int n0 = (blockIdx.x >> 2) * 128;
  const int w = tid >> 6;
  const int l = tid & 63;
  const int l15 = l & 15, lhi = l >> 4;
  const int row0 = n0 + w * 32;

  // A staging (pre-swizzled source; linear LDS dest): instr j covers rows
  // row0+j*8+(l>>3), slot (l&7)^(l>>3); lands at slot j*64+l.
  const float* aps0 = A + ((size_t)r * 8192 + (size_t)(row0 + (l >> 3))) * 8192 + (((l & 7) ^ (l >> 3)) << 2);
  const float* aps1 = aps0 + (size_t)8 * 8192;
  const float* aps2 = aps0 + (size_t)16 * 8192;
  const float* aps3 = aps0 + (size_t)24 * 8192;
  // B staging: wave w stages chunks 2w, 2w+1 of the shared 4KB tile
  const unsigned short* bsrc = xwf + (size_t)r * 524288 + (size_t)w * 1024 + (size_t)l * 8;

  char* Aw = smem + w * 16384;
  char* Bb = smem + 65536;

  // ds_read offsets: A frag rf, half b: row=rf*16+l15, slot=(2*lhi+b)^(l15&7)
  const int ao00 = ((0 * 16 + l15) * 8 + ((lhi * 2 + 0) ^ (l15 & 7))) * 16;
  const int ao01 = ((0 * 16 + l15) * 8 + ((lhi * 2 + 1) ^ (l15 & 7))) * 16;
  const int ao10 = ((1 * 16 + l15) * 8 + ((lhi * 2 + 0) ^ (l15 & 7))) * 16;
  const int ao11 = ((1 * 16 + l15) * 8 + ((lhi * 2 + 1) ^ (l15 & 7))) * 16;
  const int bo = l * 16;

  v4f acc00 = {0.f, 0.f, 0.f, 0.f}, acc01 = {0.f, 0.f, 0.f, 0.f};
  v4f acc02 = {0.f, 0.f, 0.f, 0.f}, acc03 = {0.f, 0.f, 0.f, 0.f};
  v4f acc10 = {0.f, 0.f, 0.f, 0.f}, acc11 = {0.f, 0.f, 0.f, 0.f};
  v4f acc12 = {0.f, 0.f, 0.f, 0.f}, acc13 = {0.f, 0.f, 0.f, 0.f};

  STAGE(0) STAGE(1) STAGE(2) STAGE(3)  // 24 loads in flight/wave
  for (int t = 0; t < 63; ++t) {       // steps 0..251
    STEP(0, 18, 1)
    STEP(1, 18, 1)
    STEP(2, 18, 1)
    STEP(3, 18, 1)
  }
  STEP(0, 18, 0)  // step 252
  STEP(1, 12, 0)  // step 253
  STEP(2, 6, 0)   // step 254
  STEP(3, 0, 0)   // step 255

  // epilogue: atomic-add partials (D layout: col=l&15, row=4*(l>>4)+reg)
  float* ob = out + ((size_t)row0 + lhi * 4) * 64 + l15;
  ATOM_FRAG(acc00, 0, 0)
  ATOM_FRAG(acc01, 0, 1)
  ATOM_FRAG(acc02, 0, 2)
  ATOM_FRAG(acc03, 0, 3)
  ATOM_FRAG(acc10, 1, 0)
  ATOM_FRAG(acc11, 1, 1)
  ATOM_FRAG(acc12, 1, 2)
  ATOM_FRAG(acc13, 1, 3)
}

// ---------------- kernel 3: out = relu(out) ---------------------------------
__global__ __launch_bounds__(256) void rgcn_relu(float* __restrict__ out) {
  int i = blockIdx.x * 256 + threadIdx.x;  // 512 blocks -> 131072 v4f = 2 MB
  v4f v = ((v4f*)out)[i];
  v.x = fmaxf(v.x, 0.f);
  v.y = fmaxf(v.y, 0.f);
  v.z = fmaxf(v.z, 0.f);
  v.w = fmaxf(v.w, 0.f);
  ((v4f*)out)[i] = v;
}

extern "C" void kernel_launch(void* const* d_in, const int* in_sizes, int n_in,
                              void* d_out, int out_size, void* d_ws, size_t ws_size,
                              hipStream_t stream) {
  const float* feat = (const float*)d_in[0];
  // d_in[1] = out_indices (int64) -- unused (final_layer=False returns all nodes)
  const float* adj = (const float*)d_in[2];
  const float* bases = (const float*)d_in[3];
  const float* coef = (const float*)d_in[4];
  const float* sk = (const float*)d_in[5];
  const float* bias = (const float*)d_in[6];
  float* out = (float*)d_out;

  // ws layout: [0, 4MB) xwf bf16 swizzled; [4MB, 4.25MB) W fp32
  unsigned short* xwf = (unsigned short*)d_ws;
  float* W = (float*)((char*)d_ws + (4u << 20));

  rgcn_wk<<<64, 256, 0, stream>>>(bases, coef, W);
  // selfout staged in d_out (fully rewritten each call); main atomically
  // accumulates the 4 relations onto it; relu finishes.
  rgcn_prep<<<256, 256, 0, stream>>>(feat, W, sk, bias, xwf, out);
  rgcn_main<<<256, 256, 0, stream>>>(adj, xwf, out);
  rgcn_relu<<<512, 256, 0, stream>>>(out);

  (void)in_sizes;
  (void)n_in;
  (void)out_size;
  (void)ws_size;
}

// Round 4
// 209.760 us; speedup vs baseline: 1.2260x; 1.2260x over previous
//
#include <hip/hip_runtime.h>

// RGCN: out = relu( sum_r A_r @ (X W_r) + X Sk + bias )
// N=8192, F=U=64, R=4, B=20.  A (4,8192,8192) fp32 = 1.07 GB -> HBM-bound.
// Main kernel: barrier-free per-wave async global_load_lds pipeline, depth 2,
// K-step 64 (256 B contiguous per A-row per step for DRAM page locality).

typedef float v4f __attribute__((ext_vector_type(4)));
typedef unsigned int v4u __attribute__((ext_vector_type(4)));
typedef short v8s __attribute__((ext_vector_type(8)));

__device__ __forceinline__ unsigned short f2bf(float f) {
  // round-to-nearest-even f32 -> bf16
  unsigned int u = __builtin_bit_cast(unsigned int, f);
  return (unsigned short)((u + 0x7fffu + ((u >> 16) & 1u)) >> 16);
}

__device__ __forceinline__ void gload16(const void* g, void* l) {
  __builtin_amdgcn_global_load_lds((const __attribute__((address_space(1))) void*)g,
                                   (__attribute__((address_space(3))) void*)l, 16, 0, 0);
}

// ---------------- kernel 0: W[r][f][u] = sum_k bases[f][u][k] * coef[r][k] ----
__global__ __launch_bounds__(256) void rgcn_wk(const float* __restrict__ bases,
                                               const float* __restrict__ coef,
                                               float* __restrict__ W) {
  int i = blockIdx.x * 256 + threadIdx.x;  // 64*256 = 16384 = R*F*U
  int r = i >> 12;
  int fu = i & 4095;
  float s = 0.f;
#pragma unroll
  for (int k = 0; k < 20; ++k) s += bases[fu * 20 + k] * coef[r * 20 + k];
  W[i] = s;
}

// ---------------- kernel 1: xw (bf16, swizzled to B-fragment layout) + selfout
// xwf layout: for K-32 group (r, m0=32*mb) and u-tile ut, lane l, elem j holds
//   xw[r][m0 + 8*(l>>4) + j][ut*16 + (l&15)]
//   at index ((r*256 + mb)*4 + ut)*512 + l*8 + j
__global__ __launch_bounds__(256) void rgcn_prep(const float* __restrict__ x,
                                                 const float* __restrict__ W,
                                                 const float* __restrict__ sk,
                                                 const float* __restrict__ bias,
                                                 unsigned short* __restrict__ xwf,
                                                 float* __restrict__ selfout) {
  __shared__ float lx[2048];            // 32 rows x 64 f
  __shared__ unsigned short lxw[8192];  // 4 rel x 2048 swizzled bf16
  const int t = threadIdx.x;
  const int blk = blockIdx.x;
  const int n0 = blk * 32;
  for (int i = t; i < 2048; i += 256) lx[i] = x[(size_t)n0 * 64 + i];
  __syncthreads();
  const int u = t & 63, rq = t >> 6;  // each thread: column u, rows rq*8..rq*8+7
  float acc[8][5];
#pragma unroll
  for (int p = 0; p < 8; ++p)
#pragma unroll
    for (int c = 0; c < 5; ++c) acc[p][c] = 0.f;
  const float* wu = W + u;   // W[r][f][u] = wu[r*4096 + f*64]
  const float* sku = sk + u;
#pragma unroll 4
  for (int f = 0; f < 64; ++f) {
    float w0 = wu[f * 64];
    float w1 = wu[4096 + f * 64];
    float w2 = wu[8192 + f * 64];
    float w3 = wu[12288 + f * 64];
    float w4 = sku[f * 64];
#pragma unroll
    for (int p = 0; p < 8; ++p) {
      float xv = lx[(rq * 8 + p) * 64 + f];
      acc[p][0] += xv * w0;
      acc[p][1] += xv * w1;
      acc[p][2] += xv * w2;
      acc[p][3] += xv * w3;
      acc[p][4] += xv * w4;
    }
  }
  const float bu = bias[u];
#pragma unroll
  for (int p = 0; p < 8; ++p) {
    int km = rq * 8 + p;  // local m index 0..31
    selfout[(size_t)(n0 + km) * 64 + u] = acc[p][4] + bu;
    int idx = (u >> 4) * 512 + ((km >> 3) * 16 + (u & 15)) * 8 + (km & 7);
#pragma unroll
    for (int r = 0; r < 4; ++r) lxw[r * 2048 + idx] = f2bf(acc[p][r]);
  }
  __syncthreads();
  const unsigned int* lsrc = (const unsigned int*)lxw;
  unsigned int* gdst = (unsigned int*)xwf;
  for (int i = t; i < 4096; i += 256) {  // 4 rel x 1024 dwords, coalesced
    int r = i >> 10, q = i & 1023;
    gdst[(size_t)(r * 256 + blk) * 1024 + q] = lsrc[i];
  }
}

// ---------------- kernel 2: out = relu( sum_r A_r @ xw_r + selfout ) --------
// LDS per (wave w, buf p): 16 KB at smem + (w*2+p)*16384:
//   A tile [32 rows][16 slots of 16B], phys slot = c ^ (row&7) (XOR within
//     8-slot groups); B tile at +8192: linear, chunk q at q*1024 + l*16
//     (q = g*4 + ut for K-32 group g, u-tile ut).

#define PACK8(S, X0, X1)          \
  {                               \
    S[0] = (short)f2bf(X0.x);     \
    S[1] = (short)f2bf(X0.y);     \
    S[2] = (short)f2bf(X0.z);     \
    S[3] = (short)f2bf(X0.w);     \
    S[4] = (short)f2bf(X1.x);     \
    S[5] = (short)f2bf(X1.y);     \
    S[6] = (short)f2bf(X1.z);     \
    S[7] = (short)f2bf(X1.w);     \
  }

#define STAGE(P)                                          \
  {                                                       \
    char* ab = Wb + (P)*16384;                            \
    gload16(aps0, ab);                                    \
    gload16(aps1, ab + 1024);                             \
    gload16(aps2, ab + 2048);                             \
    gload16(aps3, ab + 3072);                             \
    gload16(aps4, ab + 4096);                             \
    gload16(aps5, ab + 5120);                             \
    gload16(aps6, ab + 6144);                             \
    gload16(aps7, ab + 7168);                             \
    char* bb = ab + 8192;                                 \
    gload16(bsrc, bb);                                    \
    gload16(bsrc + 512, bb + 1024);                       \
    gload16(bsrc + 1024, bb + 2048);                      \
    gload16(bsrc + 1536, bb + 3072);                      \
    gload16(bsrc + 2048, bb + 4096);                      \
    gload16(bsrc + 2560, bb + 5120);                      \
    gload16(bsrc + 3072, bb + 6144);                      \
    gload16(bsrc + 3584, bb + 7168);                      \
    aps0 += 64; aps1 += 64; aps2 += 64; aps3 += 64;       \
    aps4 += 64; aps5 += 64; aps6 += 64; aps7 += 64;       \
    bsrc += 4096;                                         \
  }

#define MFMA8(AF0, AF1, B0, B1, B2, B3)                                          \
  {                                                                              \
    acc00 = __builtin_amdgcn_mfma_f32_16x16x32_bf16(AF0, B0, acc00, 0, 0, 0);    \
    acc01 = __builtin_amdgcn_mfma_f32_16x16x32_bf16(AF0, B1, acc01, 0, 0, 0);    \
    acc02 = __builtin_amdgcn_mfma_f32_16x16x32_bf16(AF0, B2, acc02, 0, 0, 0);    \
    acc03 = __builtin_amdgcn_mfma_f32_16x16x32_bf16(AF0, B3, acc03, 0, 0, 0);    \
    acc10 = __builtin_amdgcn_mfma_f32_16x16x32_bf16(AF1, B0, acc10, 0, 0, 0);    \
    acc11 = __builtin_amdgcn_mfma_f32_16x16x32_bf16(AF1, B1, acc11, 0, 0, 0);    \
    acc12 = __builtin_amdgcn_mfma_f32_16x16x32_bf16(AF1, B2, acc12, 0, 0, 0);    \
    acc13 = __builtin_amdgcn_mfma_f32_16x16x32_bf16(AF1, B3, acc13, 0, 0, 0);    \
  }

#define STEP(P, VMN, DO_STAGE)                                             \
  {                                                                        \
    asm volatile("s_waitcnt vmcnt(" #VMN ")" ::: "memory");                \
    __builtin_amdgcn_sched_barrier(0);                                     \
    const char* ap = Wb + (P)*16384;                                       \
    const char* bp = ap + 8192;                                            \
    v4f a000 = *(const v4f*)(ap + ao000);                                  \
    v4f a001 = *(const v4f*)(ap + ao001);                                  \
    v4f a010 = *(const v4f*)(ap + ao010);                                  \
    v4f a011 = *(const v4f*)(ap + ao011);                                  \
    v4f a100 = *(const v4f*)(ap + ao100);                                  \
    v4f a101 = *(const v4f*)(ap + ao101);                                  \
    v4f a110 = *(const v4f*)(ap + ao110);                                  \
    v4f a111 = *(const v4f*)(ap + ao111);                                  \
    v4u b00 = *(const v4u*)(bp + bo);                                      \
    v4u b01 = *(const v4u*)(bp + bo + 1024);                               \
    v4u b02 = *(const v4u*)(bp + bo + 2048);                               \
    v4u b03 = *(const v4u*)(bp + bo + 3072);                               \
    v4u b10 = *(const v4u*)(bp + bo + 4096);                               \
    v4u b11 = *(const v4u*)(bp + bo + 5120);                               \
    v4u b12 = *(const v4u*)(bp + bo + 6144);                               \
    v4u b13 = *(const v4u*)(bp + bo + 7168);                               \
    asm volatile("s_waitcnt lgkmcnt(0)" ::: "memory");                     \
    __builtin_amdgcn_sched_barrier(0);                                     \
    if (DO_STAGE) STAGE(P)                                                 \
    v8s af0, af1;                                                          \
    PACK8(af0, a000, a001);                                                \
    PACK8(af1, a010, a011);                                                \
    MFMA8(af0, af1, __builtin_bit_cast(v8s, b00), __builtin_bit_cast(v8s, b01), \
          __builtin_bit_cast(v8s, b02), __builtin_bit_cast(v8s, b03));     \
    PACK8(af0, a100, a101);                                                \
    PACK8(af1, a110, a111);                                                \
    MFMA8(af0, af1, __builtin_bit_cast(v8s, b10), __builtin_bit_cast(v8s, b11), \
          __builtin_bit_cast(v8s, b12), __builtin_bit_cast(v8s, b13));     \
  }

#define STORE_FRAG(ACC, RF, UT)                                        \
  red[w][((RF)*16 + lhi * 4 + 0) * 64 + (UT)*16 + l15] = ACC.x;        \
  red[w][((RF)*16 + lhi * 4 + 1) * 64 + (UT)*16 + l15] = ACC.y;        \
  red[w][((RF)*16 + lhi * 4 + 2) * 64 + (UT)*16 + l15] = ACC.z;        \
  red[w][((RF)*16 + lhi * 4 + 3) * 64 + (UT)*16 + l15] = ACC.w;

__global__ __launch_bounds__(256, 1) void rgcn_main(const float* __restrict__ A,
                                                    const unsigned short* __restrict__ xwf,
                                                    float* __restrict__ out) {
  __shared__ __align__(16) char smem[131072];  // 4 waves x 2 bufs x 16KB; reused for red
  const int tid = threadIdx.x;
  const int n0 = blockIdx.x * 32;
  const int w = tid >> 6;  // wave = relation
  const int l = tid & 63;
  const int l15 = l & 15, lhi = l >> 4;

  // A staging sources (pre-swizzled): instr j covers rows j*4+(l>>4), phys
  // slot l&15 holding logical slot (l&15)^(row&7); lands at LDS j*1024+l*16.
  const float* aps0;
  const float* aps1;
  const float* aps2;
  const float* aps3;
  const float* aps4;
  const float* aps5;
  const float* aps6;
  const float* aps7;
  {
    const float* base = A + ((size_t)w * 8192 + (size_t)n0) * 8192;
#define APS_INIT(J, P)                                                        \
    {                                                                         \
      int rr = (J)*4 + lhi;                                                   \
      int c = l15 ^ (rr & 7);                                                 \
      P = base + (size_t)rr * 8192 + c * 4;                                   \
    }
    APS_INIT(0, aps0) APS_INIT(1, aps1) APS_INIT(2, aps2) APS_INIT(3, aps3)
    APS_INIT(4, aps4) APS_INIT(5, aps5) APS_INIT(6, aps6) APS_INIT(7, aps7)
#undef APS_INIT
  }
  // B staging source: step t covers xwf shorts [w*524288 + t*4096, +4096)
  const unsigned short* bsrc = xwf + (size_t)w * 524288 + (size_t)l * 8;

  char* Wb = smem + w * 32768;

  // ds_read offsets: A group g, frag rf, half h:
  //   row = rf*16 + l15, logical slot c = g*8 + 2*lhi + h, phys = c^(l15&7)
#define AOFF(G, RF, H) ((((RF)*16 + l15) * 16 + (((G)*8 + 2 * lhi + (H)) ^ (l15 & 7))) * 16)
  const int ao000 = AOFF(0, 0, 0), ao001 = AOFF(0, 0, 1);
  const int ao010 = AOFF(0, 1, 0), ao011 = AOFF(0, 1, 1);
  const int ao100 = AOFF(1, 0, 0), ao101 = AOFF(1, 0, 1);
  const int ao110 = AOFF(1, 1, 0), ao111 = AOFF(1, 1, 1);
#undef AOFF
  const int bo = l * 16;

  v4f acc00 = {0.f, 0.f, 0.f, 0.f}, acc01 = {0.f, 0.f, 0.f, 0.f};
  v4f acc02 = {0.f, 0.f, 0.f, 0.f}, acc03 = {0.f, 0.f, 0.f, 0.f};
  v4f acc10 = {0.f, 0.f, 0.f, 0.f}, acc11 = {0.f, 0.f, 0.f, 0.f};
  v4f acc12 = {0.f, 0.f, 0.f, 0.f}, acc13 = {0.f, 0.f, 0.f, 0.f};

  STAGE(0)  // step 0
  STAGE(1)  // step 1
  for (int t = 0; t < 63; ++t) {
    STEP(0, 16, 1)  // compute step 2t,   stage step 2t+2
    STEP(1, 16, 1)  // compute step 2t+1, stage step 2t+3
  }
  STEP(0, 16, 0)  // step 126
  STEP(1, 0, 0)   // step 127

  // cross-relation reduction (D layout: col = l&15, row = 4*(l>>4)+reg)
  __syncthreads();
  float(*red)[2048] = (float(*)[2048])smem;
  STORE_FRAG(acc00, 0, 0)
  STORE_FRAG(acc01, 0, 1)
  STORE_FRAG(acc02, 0, 2)
  STORE_FRAG(acc03, 0, 3)
  STORE_FRAG(acc10, 1, 0)
  STORE_FRAG(acc11, 1, 1)
  STORE_FRAG(acc12, 1, 2)
  STORE_FRAG(acc13, 1, 3)
  __syncthreads();
#pragma unroll
  for (int p = 0; p < 8; ++p) {
    int i = tid + 256 * p;
    float v = red[0][i] + red[1][i] + red[2][i] + red[3][i] + out[(size_t)n0 * 64 + i];
    out[(size_t)n0 * 64 + i] = fmaxf(v, 0.f);
  }
}

extern "C" void kernel_launch(void* const* d_in, const int* in_sizes, int n_in,
                              void* d_out, int out_size, void* d_ws, size_t ws_size,
                              hipStream_t stream) {
  const float* feat = (const float*)d_in[0];
  // d_in[1] = out_indices (int64) -- unused (final_layer=False returns all nodes)
  const float* adj = (const float*)d_in[2];
  const float* bases = (const float*)d_in[3];
  const float* coef = (const float*)d_in[4];
  const float* sk = (const float*)d_in[5];
  const float* bias = (const float*)d_in[6];
  float* out = (float*)d_out;

  // ws layout: [0, 4MB) xwf bf16 swizzled; [4MB, 4.25MB) W fp32
  unsigned short* xwf = (unsigned short*)d_ws;
  float* W = (float*)((char*)d_ws + (4u << 20));

  rgcn_wk<<<64, 256, 0, stream>>>(bases, coef, W);
  // selfout is staged in d_out; fully rewritten each call before being read.
  rgcn_prep<<<256, 256, 0, stream>>>(feat, W, sk, bias, xwf, out);
  rgcn_main<<<256, 256, 0, stream>>>(adj, xwf, out);

  (void)in_sizes;
  (void)n_in;
  (void)out_size;
  (void)ws_size;
}

// Round 5
// 200.181 us; speedup vs baseline: 1.2847x; 1.0479x over previous
//
#include <hip/hip_runtime.h>

// RGCN: out = relu( sum_r A_r @ (X W_r) + X Sk + bias )
// N=8192, F=U=64, R=4, B=20.  A (4,8192,8192) fp32 = 1.07 GB -> HBM-bound.
// Main kernel: barrier-free per-wave async global_load_lds pipeline, depth 2,
// K-step 64 (256 B contiguous per A-row per step). A loads are NON-TEMPORAL
// (evict-first in L2) so the shared 4 MB xwf B-panel stays L2-resident.

typedef float v4f __attribute__((ext_vector_type(4)));
typedef unsigned int v4u __attribute__((ext_vector_type(4)));
typedef short v8s __attribute__((ext_vector_type(8)));

__device__ __forceinline__ unsigned short f2bf(float f) {
  // round-to-nearest-even f32 -> bf16
  unsigned int u = __builtin_bit_cast(unsigned int, f);
  return (unsigned short)((u + 0x7fffu + ((u >> 16) & 1u)) >> 16);
}

__device__ __forceinline__ void gload16(const void* g, void* l) {
  __builtin_amdgcn_global_load_lds((const __attribute__((address_space(1))) void*)g,
                                   (__attribute__((address_space(3))) void*)l, 16, 0, 0);
}

// non-temporal variant for the zero-reuse A stream (CPol NT bit = 2 on gfx950)
__device__ __forceinline__ void gload16nt(const void* g, void* l) {
  __builtin_amdgcn_global_load_lds((const __attribute__((address_space(1))) void*)g,
                                   (__attribute__((address_space(3))) void*)l, 16, 0, 2);
}

// ---------------- kernel 0: W[r][f][u] = sum_k bases[f][u][k] * coef[r][k] ----
__global__ __launch_bounds__(256) void rgcn_wk(const float* __restrict__ bases,
                                               const float* __restrict__ coef,
                                               float* __restrict__ W) {
  int i = blockIdx.x * 256 + threadIdx.x;  // 64*256 = 16384 = R*F*U
  int r = i >> 12;
  int fu = i & 4095;
  float s = 0.f;
#pragma unroll
  for (int k = 0; k < 20; ++k) s += bases[fu * 20 + k] * coef[r * 20 + k];
  W[i] = s;
}

// ---------------- kernel 1: xw (bf16, swizzled to B-fragment layout) + selfout
// xwf layout: for K-32 group (r, m0=32*mb) and u-tile ut, lane l, elem j holds
//   xw[r][m0 + 8*(l>>4) + j][ut*16 + (l&15)]
//   at index ((r*256 + mb)*4 + ut)*512 + l*8 + j
__global__ __launch_bounds__(256) void rgcn_prep(const float* __restrict__ x,
                                                 const float* __restrict__ W,
                                                 const float* __restrict__ sk,
                                                 const float* __restrict__ bias,
                                                 unsigned short* __restrict__ xwf,
                                                 float* __restrict__ selfout) {
  __shared__ float lx[2048];            // 32 rows x 64 f
  __shared__ unsigned short lxw[8192];  // 4 rel x 2048 swizzled bf16
  const int t = threadIdx.x;
  const int blk = blockIdx.x;
  const int n0 = blk * 32;
  for (int i = t; i < 2048; i += 256) lx[i] = x[(size_t)n0 * 64 + i];
  __syncthreads();
  const int u = t & 63, rq = t >> 6;  // each thread: column u, rows rq*8..rq*8+7
  float acc[8][5];
#pragma unroll
  for (int p = 0; p < 8; ++p)
#pragma unroll
    for (int c = 0; c < 5; ++c) acc[p][c] = 0.f;
  const float* wu = W + u;   // W[r][f][u] = wu[r*4096 + f*64]
  const float* sku = sk + u;
#pragma unroll 4
  for (int f = 0; f < 64; ++f) {
    float w0 = wu[f * 64];
    float w1 = wu[4096 + f * 64];
    float w2 = wu[8192 + f * 64];
    float w3 = wu[12288 + f * 64];
    float w4 = sku[f * 64];
#pragma unroll
    for (int p = 0; p < 8; ++p) {
      float xv = lx[(rq * 8 + p) * 64 + f];
      acc[p][0] += xv * w0;
      acc[p][1] += xv * w1;
      acc[p][2] += xv * w2;
      acc[p][3] += xv * w3;
      acc[p][4] += xv * w4;
    }
  }
  const float bu = bias[u];
#pragma unroll
  for (int p = 0; p < 8; ++p) {
    int km = rq * 8 + p;  // local m index 0..31
    selfout[(size_t)(n0 + km) * 64 + u] = acc[p][4] + bu;
    int idx = (u >> 4) * 512 + ((km >> 3) * 16 + (u & 15)) * 8 + (km & 7);
#pragma unroll
    for (int r = 0; r < 4; ++r) lxw[r * 2048 + idx] = f2bf(acc[p][r]);
  }
  __syncthreads();
  const unsigned int* lsrc = (const unsigned int*)lxw;
  unsigned int* gdst = (unsigned int*)xwf;
  for (int i = t; i < 4096; i += 256) {  // 4 rel x 1024 dwords, coalesced
    int r = i >> 10, q = i & 1023;
    gdst[(size_t)(r * 256 + blk) * 1024 + q] = lsrc[i];
  }
}

// ---------------- kernel 2: out = relu( sum_r A_r @ xw_r + selfout ) --------
// LDS per (wave w, buf p): 16 KB at smem + (w*2+p)*16384:
//   A tile [32 rows][16 slots of 16B], phys slot = c ^ (row&7) (XOR within
//     8-slot groups); B tile at +8192: linear, chunk q at q*1024 + l*16
//     (q = g*4 + ut for K-32 group g, u-tile ut).

#define PACK8(S, X0, X1)          \
  {                               \
    S[0] = (short)f2bf(X0.x);     \
    S[1] = (short)f2bf(X0.y);     \
    S[2] = (short)f2bf(X0.z);     \
    S[3] = (short)f2bf(X0.w);     \
    S[4] = (short)f2bf(X1.x);     \
    S[5] = (short)f2bf(X1.y);     \
    S[6] = (short)f2bf(X1.z);     \
    S[7] = (short)f2bf(X1.w);     \
  }

#define STAGE(P)                                          \
  {                                                       \
    char* ab = Wb + (P)*16384;                            \
    gload16nt(aps0, ab);                                  \
    gload16nt(aps1, ab + 1024);                           \
    gload16nt(aps2, ab + 2048);                           \
    gload16nt(aps3, ab + 3072);                           \
    gload16nt(aps4, ab + 4096);                           \
    gload16nt(aps5, ab + 5120);                           \
    gload16nt(aps6, ab + 6144);                           \
    gload16nt(aps7, ab + 7168);                           \
    char* bb = ab + 8192;                                 \
    gload16(bsrc, bb);                                    \
    gload16(bsrc + 512, bb + 1024);                       \
    gload16(bsrc + 1024, bb + 2048);                      \
    gload16(bsrc + 1536, bb + 3072);                      \
    gload16(bsrc + 2048, bb + 4096);                      \
    gload16(bsrc + 2560, bb + 5120);                      \
    gload16(bsrc + 3072, bb + 6144);                      \
    gload16(bsrc + 3584, bb + 7168);                      \
    aps0 += 64; aps1 += 64; aps2 += 64; aps3 += 64;       \
    aps4 += 64; aps5 += 64; aps6 += 64; aps7 += 64;       \
    bsrc += 4096;                                         \
  }

#define MFMA8(AF0, AF1, B0, B1, B2, B3)                                          \
  {                                                                              \
    acc00 = __builtin_amdgcn_mfma_f32_16x16x32_bf16(AF0, B0, acc00, 0, 0, 0);    \
    acc01 = __builtin_amdgcn_mfma_f32_16x16x32_bf16(AF0, B1, acc01, 0, 0, 0);    \
    acc02 = __builtin_amdgcn_mfma_f32_16x16x32_bf16(AF0, B2, acc02, 0, 0, 0);    \
    acc03 = __builtin_amdgcn_mfma_f32_16x16x32_bf16(AF0, B3, acc03, 0, 0, 0);    \
    acc10 = __builtin_amdgcn_mfma_f32_16x16x32_bf16(AF1, B0, acc10, 0, 0, 0);    \
    acc11 = __builtin_amdgcn_mfma_f32_16x16x32_bf16(AF1, B1, acc11, 0, 0, 0);    \
    acc12 = __builtin_amdgcn_mfma_f32_16x16x32_bf16(AF1, B2, acc12, 0, 0, 0);    \
    acc13 = __builtin_amdgcn_mfma_f32_16x16x32_bf16(AF1, B3, acc13, 0, 0, 0);    \
  }

#define STEP(P, VMN, DO_STAGE)                                             \
  {                                                                        \
    asm volatile("s_waitcnt vmcnt(" #VMN ")" ::: "memory");                \
    __builtin_amdgcn_sched_barrier(0);                                     \
    const char* ap = Wb + (P)*16384;                                       \
    const char* bp = ap + 8192;                                            \
    v4f a000 = *(const v4f*)(ap + ao000);                                  \
    v4f a001 = *(const v4f*)(ap + ao001);                                  \
    v4f a010 = *(const v4f*)(ap + ao010);                                  \
    v4f a011 = *(const v4f*)(ap + ao011);                                  \
    v4f a100 = *(const v4f*)(ap + ao100);                                  \
    v4f a101 = *(const v4f*)(ap + ao101);                                  \
    v4f a110 = *(const v4f*)(ap + ao110);                                  \
    v4f a111 = *(const v4f*)(ap + ao111);                                  \
    v4u b00 = *(const v4u*)(bp + bo);                                      \
    v4u b01 = *(const v4u*)(bp + bo + 1024);                               \
    v4u b02 = *(const v4u*)(bp + bo + 2048);                               \
    v4u b03 = *(const v4u*)(bp + bo + 3072);                               \
    v4u b10 = *(const v4u*)(bp + bo + 4096);                               \
    v4u b11 = *(const v4u*)(bp + bo + 5120);                               \
    v4u b12 = *(const v4u*)(bp + bo + 6144);                               \
    v4u b13 = *(const v4u*)(bp + bo + 7168);                               \
    asm volatile("s_waitcnt lgkmcnt(0)" ::: "memory");                     \
    __builtin_amdgcn_sched_barrier(0);                                     \
    if (DO_STAGE) STAGE(P)                                                 \
    v8s af0, af1;                                                          \
    PACK8(af0, a000, a001);                                                \
    PACK8(af1, a010, a011);                                                \
    MFMA8(af0, af1, __builtin_bit_cast(v8s, b00), __builtin_bit_cast(v8s, b01), \
          __builtin_bit_cast(v8s, b02), __builtin_bit_cast(v8s, b03));     \
    PACK8(af0, a100, a101);                                                \
    PACK8(af1, a110, a111);                                                \
    MFMA8(af0, af1, __builtin_bit_cast(v8s, b10), __builtin_bit_cast(v8s, b11), \
          __builtin_bit_cast(v8s, b12), __builtin_bit_cast(v8s, b13));     \
  }

#define STORE_FRAG(ACC, RF, UT)                                        \
  red[w][((RF)*16 + lhi * 4 + 0) * 64 + (UT)*16 + l15] = ACC.x;        \
  red[w][((RF)*16 + lhi * 4 + 1) * 64 + (UT)*16 + l15] = ACC.y;        \
  red[w][((RF)*16 + lhi * 4 + 2) * 64 + (UT)*16 + l15] = ACC.z;        \
  red[w][((RF)*16 + lhi * 4 + 3) * 64 + (UT)*16 + l15] = ACC.w;

__global__ __launch_bounds__(256, 1) void rgcn_main(const float* __restrict__ A,
                                                    const unsigned short* __restrict__ xwf,
                                                    float* __restrict__ out) {
  __shared__ __align__(16) char smem[131072];  // 4 waves x 2 bufs x 16KB; reused for red
  const int tid = threadIdx.x;
  const int n0 = blockIdx.x * 32;
  const int w = tid >> 6;  // wave = relation
  const int l = tid & 63;
  const int l15 = l & 15, lhi = l >> 4;

  // A staging sources (pre-swizzled): instr j covers rows j*4+(l>>4), phys
  // slot l&15 holding logical slot (l&15)^(row&7); lands at LDS j*1024+l*16.
  const float* aps0;
  const float* aps1;
  const float* aps2;
  const float* aps3;
  const float* aps4;
  const float* aps5;
  const float* aps6;
  const float* aps7;
  {
    const float* base = A + ((size_t)w * 8192 + (size_t)n0) * 8192;
#define APS_INIT(J, P)                                                        \
    {                                                                         \
      int rr = (J)*4 + lhi;                                                   \
      int c = l15 ^ (rr & 7);                                                 \
      P = base + (size_t)rr * 8192 + c * 4;                                   \
    }
    APS_INIT(0, aps0) APS_INIT(1, aps1) APS_INIT(2, aps2) APS_INIT(3, aps3)
    APS_INIT(4, aps4) APS_INIT(5, aps5) APS_INIT(6, aps6) APS_INIT(7, aps7)
#undef APS_INIT
  }
  // B staging source: step t covers xwf shorts [w*524288 + t*4096, +4096)
  const unsigned short* bsrc = xwf + (size_t)w * 524288 + (size_t)l * 8;

  char* Wb = smem + w * 32768;

  // ds_read offsets: A group g, frag rf, half h:
  //   row = rf*16 + l15, logical slot c = g*8 + 2*lhi + h, phys = c^(l15&7)
#define AOFF(G, RF, H) ((((RF)*16 + l15) * 16 + (((G)*8 + 2 * lhi + (H)) ^ (l15 & 7))) * 16)
  const int ao000 = AOFF(0, 0, 0), ao001 = AOFF(0, 0, 1);
  const int ao010 = AOFF(0, 1, 0), ao011 = AOFF(0, 1, 1);
  const int ao100 = AOFF(1, 0, 0), ao101 = AOFF(1, 0, 1);
  const int ao110 = AOFF(1, 1, 0), ao111 = AOFF(1, 1, 1);
#undef AOFF
  const int bo = l * 16;

  v4f acc00 = {0.f, 0.f, 0.f, 0.f}, acc01 = {0.f, 0.f, 0.f, 0.f};
  v4f acc02 = {0.f, 0.f, 0.f, 0.f}, acc03 = {0.f, 0.f, 0.f, 0.f};
  v4f acc10 = {0.f, 0.f, 0.f, 0.f}, acc11 = {0.f, 0.f, 0.f, 0.f};
  v4f acc12 = {0.f, 0.f, 0.f, 0.f}, acc13 = {0.f, 0.f, 0.f, 0.f};

  STAGE(0)  // step 0
  STAGE(1)  // step 1
  for (int t = 0; t < 63; ++t) {
    STEP(0, 16, 1)  // compute step 2t,   stage step 2t+2
    STEP(1, 16, 1)  // compute step 2t+1, stage step 2t+3
  }
  STEP(0, 16, 0)  // step 126
  STEP(1, 0, 0)   // step 127

  // cross-relation reduction (D layout: col = l&15, row = 4*(l>>4)+reg)
  __syncthreads();
  float(*red)[2048] = (float(*)[2048])smem;
  STORE_FRAG(acc00, 0, 0)
  STORE_FRAG(acc01, 0, 1)
  STORE_FRAG(acc02, 0, 2)
  STORE_FRAG(acc03, 0, 3)
  STORE_FRAG(acc10, 1, 0)
  STORE_FRAG(acc11, 1, 1)
  STORE_FRAG(acc12, 1, 2)
  STORE_FRAG(acc13, 1, 3)
  __syncthreads();
#pragma unroll
  for (int p = 0; p < 8; ++p) {
    int i = tid + 256 * p;
    float v = red[0][i] + red[1][i] + red[2][i] + red[3][i] + out[(size_t)n0 * 64 + i];
    out[(size_t)n0 * 64 + i] = fmaxf(v, 0.f);
  }
}

extern "C" void kernel_launch(void* const* d_in, const int* in_sizes, int n_in,
                              void* d_out, int out_size, void* d_ws, size_t ws_size,
                              hipStream_t stream) {
  const float* feat = (const float*)d_in[0];
  // d_in[1] = out_indices (int64) -- unused (final_layer=False returns all nodes)
  const float* adj = (const float*)d_in[2];
  const float* bases = (const float*)d_in[3];
  const float* coef = (const float*)d_in[4];
  const float* sk = (const float*)d_in[5];
  const float* bias = (const float*)d_in[6];
  float* out = (float*)d_out;

  // ws layout: [0, 4MB) xwf bf16 swizzled; [4MB, 4.25MB) W fp32
  unsigned short* xwf = (unsigned short*)d_ws;
  float* W = (float*)((char*)d_ws + (4u << 20));

  rgcn_wk<<<64, 256, 0, stream>>>(bases, coef, W);
  // selfout is staged in d_out; fully rewritten each call before being read.
  rgcn_prep<<<256, 256, 0, stream>>>(feat, W, sk, bias, xwf, out);
  rgcn_main<<<256, 256, 0, stream>>>(adj, xwf, out);

  (void)in_sizes;
  (void)n_in;
  (void)out_size;
  (void)ws_size;
}

// Round 6
// 194.968 us; speedup vs baseline: 1.3190x; 1.0267x over previous
//
#include <hip/hip_runtime.h>

// RGCN: out = relu( sum_r A_r @ (X W_r) + X Sk + bias )
// N=8192, F=U=64, R=4, B=20.  A (4,8192,8192) fp32 = 1.07 GB -> HBM-bound.
// Main kernel: barrier-free per-wave async pipeline, depth 2, K-step 128
// (512 B contiguous per A-row per step). A: global_load_lds NON-TEMPORAL into
// XOR-swizzled LDS. B: direct global->VGPR loads (xwf is already in fragment
// layout; LDS round-trip removed).

typedef float v4f __attribute__((ext_vector_type(4)));
typedef unsigned int v4u __attribute__((ext_vector_type(4)));
typedef short v8s __attribute__((ext_vector_type(8)));

__device__ __forceinline__ unsigned short f2bf(float f) {
  // round-to-nearest-even f32 -> bf16
  unsigned int u = __builtin_bit_cast(unsigned int, f);
  return (unsigned short)((u + 0x7fffu + ((u >> 16) & 1u)) >> 16);
}

// non-temporal global->LDS for the zero-reuse A stream (CPol NT bit = 2)
__device__ __forceinline__ void gload16nt(const void* g, void* l) {
  __builtin_amdgcn_global_load_lds((const __attribute__((address_space(1))) void*)g,
                                   (__attribute__((address_space(3))) void*)l, 16, 0, 2);
}

// ---------------- kernel 0: W[r][f][u] = sum_k bases[f][u][k] * coef[r][k] ----
__global__ __launch_bounds__(256) void rgcn_wk(const float* __restrict__ bases,
                                               const float* __restrict__ coef,
                                               float* __restrict__ W) {
  int i = blockIdx.x * 256 + threadIdx.x;  // 64*256 = 16384 = R*F*U
  int r = i >> 12;
  int fu = i & 4095;
  float s = 0.f;
#pragma unroll
  for (int k = 0; k < 20; ++k) s += bases[fu * 20 + k] * coef[r * 20 + k];
  W[i] = s;
}

// ---------------- kernel 1: xw (bf16, swizzled to B-fragment layout) + selfout
// xwf layout: for K-32 group (r, m0=32*mb) and u-tile ut, lane l, elem j holds
//   xw[r][m0 + 8*(l>>4) + j][ut*16 + (l&15)]
//   at index ((r*256 + mb)*4 + ut)*512 + l*8 + j
__global__ __launch_bounds__(256) void rgcn_prep(const float* __restrict__ x,
                                                 const float* __restrict__ W,
                                                 const float* __restrict__ sk,
                                                 const float* __restrict__ bias,
                                                 unsigned short* __restrict__ xwf,
                                                 float* __restrict__ selfout) {
  __shared__ float lx[2048];            // 32 rows x 64 f
  __shared__ unsigned short lxw[8192];  // 4 rel x 2048 swizzled bf16
  const int t = threadIdx.x;
  const int blk = blockIdx.x;
  const int n0 = blk * 32;
  for (int i = t; i < 2048; i += 256) lx[i] = x[(size_t)n0 * 64 + i];
  __syncthreads();
  const int u = t & 63, rq = t >> 6;  // each thread: column u, rows rq*8..rq*8+7
  float acc[8][5];
#pragma unroll
  for (int p = 0; p < 8; ++p)
#pragma unroll
    for (int c = 0; c < 5; ++c) acc[p][c] = 0.f;
  const float* wu = W + u;   // W[r][f][u] = wu[r*4096 + f*64]
  const float* sku = sk + u;
#pragma unroll 4
  for (int f = 0; f < 64; ++f) {
    float w0 = wu[f * 64];
    float w1 = wu[4096 + f * 64];
    float w2 = wu[8192 + f * 64];
    float w3 = wu[12288 + f * 64];
    float w4 = sku[f * 64];
#pragma unroll
    for (int p = 0; p < 8; ++p) {
      float xv = lx[(rq * 8 + p) * 64 + f];
      acc[p][0] += xv * w0;
      acc[p][1] += xv * w1;
      acc[p][2] += xv * w2;
      acc[p][3] += xv * w3;
      acc[p][4] += xv * w4;
    }
  }
  const float bu = bias[u];
#pragma unroll
  for (int p = 0; p < 8; ++p) {
    int km = rq * 8 + p;  // local m index 0..31
    selfout[(size_t)(n0 + km) * 64 + u] = acc[p][4] + bu;
    int idx = (u >> 4) * 512 + ((km >> 3) * 16 + (u & 15)) * 8 + (km & 7);
#pragma unroll
    for (int r = 0; r < 4; ++r) lxw[r * 2048 + idx] = f2bf(acc[p][r]);
  }
  __syncthreads();
  const unsigned int* lsrc = (const unsigned int*)lxw;
  unsigned int* gdst = (unsigned int*)xwf;
  for (int i = t; i < 4096; i += 256) {  // 4 rel x 1024 dwords, coalesced
    int r = i >> 10, q = i & 1023;
    gdst[(size_t)(r * 256 + blk) * 1024 + q] = lsrc[i];
  }
}

// ---------------- kernel 2: out = relu( sum_r A_r @ xw_r + selfout ) --------
// LDS per (wave w, buf p): 16 KB at smem + w*32768 + p*16384:
//   A tile [32 rows][32 slots of 16B], phys slot = c ^ (row&7) (XOR within
//   8-slot groups). B: no LDS -- double-buffered in VGPRs (sets b0_*, b1_*).

#define PACK8(S, X0, X1)          \
  {                               \
    S[0] = (short)f2bf(X0.x);     \
    S[1] = (short)f2bf(X0.y);     \
    S[2] = (short)f2bf(X0.z);     \
    S[3] = (short)f2bf(X0.w);     \
    S[4] = (short)f2bf(X1.x);     \
    S[5] = (short)f2bf(X1.y);     \
    S[6] = (short)f2bf(X1.z);     \
    S[7] = (short)f2bf(X1.w);     \
  }

#define STAGE_A(P)                                        \
  {                                                       \
    char* ab = Wb + (P)*16384;                            \
    gload16nt(aps0, ab);                                  \
    gload16nt(aps1, ab + 1024);                           \
    gload16nt(aps2, ab + 2048);                           \
    gload16nt(aps3, ab + 3072);                           \
    gload16nt(aps4, ab + 4096);                           \
    gload16nt(aps5, ab + 5120);                           \
    gload16nt(aps6, ab + 6144);                           \
    gload16nt(aps7, ab + 7168);                           \
    gload16nt(aps8, ab + 8192);                           \
    gload16nt(aps9, ab + 9216);                           \
    gload16nt(aps10, ab + 10240);                         \
    gload16nt(aps11, ab + 11264);                         \
    gload16nt(aps12, ab + 12288);                         \
    gload16nt(aps13, ab + 13312);                         \
    gload16nt(aps14, ab + 14336);                         \
    gload16nt(aps15, ab + 15360);                         \
    aps0 += 128; aps1 += 128; aps2 += 128; aps3 += 128;   \
    aps4 += 128; aps5 += 128; aps6 += 128; aps7 += 128;   \
    aps8 += 128; aps9 += 128; aps10 += 128; aps11 += 128; \
    aps12 += 128; aps13 += 128; aps14 += 128; aps15 += 128; \
  }

#define BLOAD(P)                                    \
  {                                                 \
    b##P##_00 = *(const v4u*)(bsrc);                \
    b##P##_01 = *(const v4u*)(bsrc + 512);          \
    b##P##_02 = *(const v4u*)(bsrc + 1024);         \
    b##P##_03 = *(const v4u*)(bsrc + 1536);         \
    b##P##_10 = *(const v4u*)(bsrc + 2048);         \
    b##P##_11 = *(const v4u*)(bsrc + 2560);         \
    b##P##_12 = *(const v4u*)(bsrc + 3072);         \
    b##P##_13 = *(const v4u*)(bsrc + 3584);         \
    b##P##_20 = *(const v4u*)(bsrc + 4096);         \
    b##P##_21 = *(const v4u*)(bsrc + 4608);         \
    b##P##_22 = *(const v4u*)(bsrc + 5120);         \
    b##P##_23 = *(const v4u*)(bsrc + 5632);         \
    b##P##_30 = *(const v4u*)(bsrc + 6144);         \
    b##P##_31 = *(const v4u*)(bsrc + 6656);         \
    b##P##_32 = *(const v4u*)(bsrc + 7168);         \
    b##P##_33 = *(const v4u*)(bsrc + 7680);         \
    bsrc += 8192;                                   \
  }

#define MFMA8(AF0, AF1, B0, B1, B2, B3)                                          \
  {                                                                              \
    acc00 = __builtin_amdgcn_mfma_f32_16x16x32_bf16(AF0, B0, acc00, 0, 0, 0);    \
    acc01 = __builtin_amdgcn_mfma_f32_16x16x32_bf16(AF0, B1, acc01, 0, 0, 0);    \
    acc02 = __builtin_amdgcn_mfma_f32_16x16x32_bf16(AF0, B2, acc02, 0, 0, 0);    \
    acc03 = __builtin_amdgcn_mfma_f32_16x16x32_bf16(AF0, B3, acc03, 0, 0, 0);    \
    acc10 = __builtin_amdgcn_mfma_f32_16x16x32_bf16(AF1, B0, acc10, 0, 0, 0);    \
    acc11 = __builtin_amdgcn_mfma_f32_16x16x32_bf16(AF1, B1, acc11, 0, 0, 0);    \
    acc12 = __builtin_amdgcn_mfma_f32_16x16x32_bf16(AF1, B2, acc12, 0, 0, 0);    \
    acc13 = __builtin_amdgcn_mfma_f32_16x16x32_bf16(AF1, B3, acc13, 0, 0, 0);    \
  }

#define BC(X) __builtin_bit_cast(v8s, X)

#define STEP(P, VMN, DO_STAGE)                                             \
  {                                                                        \
    asm volatile("s_waitcnt vmcnt(" #VMN ")" ::: "memory");                \
    __builtin_amdgcn_sched_barrier(0);                                     \
    const char* ap = Wb + (P)*16384;                                       \
    v4f a000 = *(const v4f*)(ap + ao000);                                  \
    v4f a001 = *(const v4f*)(ap + ao001);                                  \
    v4f a010 = *(const v4f*)(ap + ao010);                                  \
    v4f a011 = *(const v4f*)(ap + ao011);                                  \
    v4f a100 = *(const v4f*)(ap + ao100);                                  \
    v4f a101 = *(const v4f*)(ap + ao101);                                  \
    v4f a110 = *(const v4f*)(ap + ao110);                                  \
    v4f a111 = *(const v4f*)(ap + ao111);                                  \
    v4f a200 = *(const v4f*)(ap + ao200);                                  \
    v4f a201 = *(const v4f*)(ap + ao201);                                  \
    v4f a210 = *(const v4f*)(ap + ao210);                                  \
    v4f a211 = *(const v4f*)(ap + ao211);                                  \
    v4f a300 = *(const v4f*)(ap + ao300);                                  \
    v4f a301 = *(const v4f*)(ap + ao301);                                  \
    v4f a310 = *(const v4f*)(ap + ao310);                                  \
    v4f a311 = *(const v4f*)(ap + ao311);                                  \
    asm volatile("s_waitcnt lgkmcnt(0)" ::: "memory");                     \
    __builtin_amdgcn_sched_barrier(0);                                     \
    if (DO_STAGE) STAGE_A(P)                                               \
    v8s af0, af1;                                                          \
    PACK8(af0, a000, a001);                                                \
    PACK8(af1, a010, a011);                                                \
    MFMA8(af0, af1, BC(b##P##_00), BC(b##P##_01), BC(b##P##_02), BC(b##P##_03)); \
    PACK8(af0, a100, a101);                                                \
    PACK8(af1, a110, a111);                                                \
    MFMA8(af0, af1, BC(b##P##_10), BC(b##P##_11), BC(b##P##_12), BC(b##P##_13)); \
    PACK8(af0, a200, a201);                                                \
    PACK8(af1, a210, a211);                                                \
    MFMA8(af0, af1, BC(b##P##_20), BC(b##P##_21), BC(b##P##_22), BC(b##P##_23)); \
    PACK8(af0, a300, a301);                                                \
    PACK8(af1, a310, a311);                                                \
    MFMA8(af0, af1, BC(b##P##_30), BC(b##P##_31), BC(b##P##_32), BC(b##P##_33)); \
    if (DO_STAGE) BLOAD(P)                                                 \
  }

#define STORE_FRAG(ACC, RF, UT)                                        \
  red[w][((RF)*16 + lhi * 4 + 0) * 64 + (UT)*16 + l15] = ACC.x;        \
  red[w][((RF)*16 + lhi * 4 + 1) * 64 + (UT)*16 + l15] = ACC.y;        \
  red[w][((RF)*16 + lhi * 4 + 2) * 64 + (UT)*16 + l15] = ACC.z;        \
  red[w][((RF)*16 + lhi * 4 + 3) * 64 + (UT)*16 + l15] = ACC.w;

__global__ __launch_bounds__(256, 1) void rgcn_main(const float* __restrict__ A,
                                                    const unsigned short* __restrict__ xwf,
                                                    float* __restrict__ out) {
  __shared__ __align__(16) char smem[131072];  // 4 waves x 2 bufs x 16KB (A only)
  const int tid = threadIdx.x;
  const int n0 = blockIdx.x * 32;
  const int w = tid >> 6;  // wave = relation
  const int l = tid & 63;
  const int l15 = l & 15, lhi = l >> 4;

  // A staging sources (pre-swizzled): instr J covers tile rows 2J+(l>>5);
  // lane's phys slot l&31 holds logical slot (l&31)^(row&7); LDS dest is
  // linear J*1024 + l*16. Each instr reads 2 x 512 B contiguous segments.
  const float* aps0;  const float* aps1;  const float* aps2;  const float* aps3;
  const float* aps4;  const float* aps5;  const float* aps6;  const float* aps7;
  const float* aps8;  const float* aps9;  const float* aps10; const float* aps11;
  const float* aps12; const float* aps13; const float* aps14; const float* aps15;
  {
    const float* base = A + ((size_t)w * 8192 + (size_t)n0) * 8192;
#define APS_INIT(J, PTR)                                                      \
    {                                                                         \
      int rr = (J)*2 + (l >> 5);                                              \
      int c = (l & 31) ^ (rr & 7);                                            \
      PTR = base + (size_t)rr * 8192 + c * 4;                                 \
    }
    APS_INIT(0, aps0)   APS_INIT(1, aps1)   APS_INIT(2, aps2)   APS_INIT(3, aps3)
    APS_INIT(4, aps4)   APS_INIT(5, aps5)   APS_INIT(6, aps6)   APS_INIT(7, aps7)
    APS_INIT(8, aps8)   APS_INIT(9, aps9)   APS_INIT(10, aps10) APS_INIT(11, aps11)
    APS_INIT(12, aps12) APS_INIT(13, aps13) APS_INIT(14, aps14) APS_INIT(15, aps15)
#undef APS_INIT
  }
  // B source: step t covers xwf shorts [w*524288 + t*8192, +8192)
  const unsigned short* bsrc = xwf + (size_t)w * 524288 + (size_t)l * 8;

  char* Wb = smem + w * 32768;

  // ds_read offsets: k-group g (0..3), frag rf, half h:
  //   row = rf*16 + l15, logical slot c = g*8 + 2*lhi + h, phys = c^(l15&7)
#define AOFF(G, RF, H) ((((RF)*16 + l15) * 32 + (((G)*8 + 2 * lhi + (H)) ^ (l15 & 7))) * 16)
  const int ao000 = AOFF(0, 0, 0), ao001 = AOFF(0, 0, 1);
  const int ao010 = AOFF(0, 1, 0), ao011 = AOFF(0, 1, 1);
  const int ao100 = AOFF(1, 0, 0), ao101 = AOFF(1, 0, 1);
  const int ao110 = AOFF(1, 1, 0), ao111 = AOFF(1, 1, 1);
  const int ao200 = AOFF(2, 0, 0), ao201 = AOFF(2, 0, 1);
  const int ao210 = AOFF(2, 1, 0), ao211 = AOFF(2, 1, 1);
  const int ao300 = AOFF(3, 0, 0), ao301 = AOFF(3, 0, 1);
  const int ao310 = AOFF(3, 1, 0), ao311 = AOFF(3, 1, 1);
#undef AOFF

  // B register double-buffer (2 sets x 16 v4u)
  v4u b0_00, b0_01, b0_02, b0_03, b0_10, b0_11, b0_12, b0_13;
  v4u b0_20, b0_21, b0_22, b0_23, b0_30, b0_31, b0_32, b0_33;
  v4u b1_00, b1_01, b1_02, b1_03, b1_10, b1_11, b1_12, b1_13;
  v4u b1_20, b1_21, b1_22, b1_23, b1_30, b1_31, b1_32, b1_33;

  v4f acc00 = {0.f, 0.f, 0.f, 0.f}, acc01 = {0.f, 0.f, 0.f, 0.f};
  v4f acc02 = {0.f, 0.f, 0.f, 0.f}, acc03 = {0.f, 0.f, 0.f, 0.f};
  v4f acc10 = {0.f, 0.f, 0.f, 0.f}, acc11 = {0.f, 0.f, 0.f, 0.f};
  v4f acc12 = {0.f, 0.f, 0.f, 0.f}, acc13 = {0.f, 0.f, 0.f, 0.f};

  STAGE_A(0) BLOAD(0)  // step 0
  STAGE_A(1) BLOAD(1)  // step 1
  for (int t = 0; t < 31; ++t) {
    STEP(0, 32, 1)  // compute step 2t,   stage step 2t+2
    STEP(1, 32, 1)  // compute step 2t+1, stage step 2t+3
  }
  STEP(0, 32, 0)  // step 62
  STEP(1, 0, 0)   // step 63

  // cross-relation reduction (D layout: col = l&15, row = 4*(l>>4)+reg)
  __syncthreads();
  float(*red)[2048] = (float(*)[2048])smem;
  STORE_FRAG(acc00, 0, 0)
  STORE_FRAG(acc01, 0, 1)
  STORE_FRAG(acc02, 0, 2)
  STORE_FRAG(acc03, 0, 3)
  STORE_FRAG(acc10, 1, 0)
  STORE_FRAG(acc11, 1, 1)
  STORE_FRAG(acc12, 1, 2)
  STORE_FRAG(acc13, 1, 3)
  __syncthreads();
#pragma unroll
  for (int p = 0; p < 8; ++p) {
    int i = tid + 256 * p;
    float v = red[0][i] + red[1][i] + red[2][i] + red[3][i] + out[(size_t)n0 * 64 + i];
    out[(size_t)n0 * 64 + i] = fmaxf(v, 0.f);
  }
}

extern "C" void kernel_launch(void* const* d_in, const int* in_sizes, int n_in,
                              void* d_out, int out_size, void* d_ws, size_t ws_size,
                              hipStream_t stream) {
  const float* feat = (const float*)d_in[0];
  // d_in[1] = out_indices (int64) -- unused (final_layer=False returns all nodes)
  const float* adj = (const float*)d_in[2];
  const float* bases = (const float*)d_in[3];
  const float* coef = (const float*)d_in[4];
  const float* sk = (const float*)d_in[5];
  const float* bias = (const float*)d_in[6];
  float* out = (float*)d_out;

  // ws layout: [0, 4MB) xwf bf16 swizzled; [4MB, 4.25MB) W fp32
  unsigned short* xwf = (unsigned short*)d_ws;
  float* W = (float*)((char*)d_ws + (4u << 20));

  rgcn_wk<<<64, 256, 0, stream>>>(bases, coef, W);
  // selfout is staged in d_out; fully rewritten each call before being read.
  rgcn_prep<<<256, 256, 0, stream>>>(feat, W, sk, bias, xwf, out);
  rgcn_main<<<256, 256, 0, stream>>>(adj, xwf, out);

  (void)in_sizes;
  (void)n_in;
  (void)out_size;
  (void)ws_size;
}

// Round 7
// 185.666 us; speedup vs baseline: 1.3851x; 1.0501x over previous
//
#include <hip/hip_runtime.h>

// RGCN: out = relu( sum_r A_r @ (X W_r) + X Sk + bias )
// N=8192, F=U=64, R=4, B=20.  A (4,8192,8192) fp32 = 1.07 GB -> HBM-bound.
// Main kernel (UNCHANGED from round 6): barrier-free per-wave async pipeline,
// depth 2, K-step 128, A via NT global_load_lds into XOR-swizzled LDS, B
// direct global->VGPR. This round: prep rewritten with MFMA (was VALU-bound
// fp32 GEMM, ~4.3 us floor on vector ALU).

typedef float v4f __attribute__((ext_vector_type(4)));
typedef unsigned int v4u __attribute__((ext_vector_type(4)));
typedef short v8s __attribute__((ext_vector_type(8)));

__device__ __forceinline__ unsigned short f2bf(float f) {
  // round-to-nearest-even f32 -> bf16
  unsigned int u = __builtin_bit_cast(unsigned int, f);
  return (unsigned short)((u + 0x7fffu + ((u >> 16) & 1u)) >> 16);
}

// non-temporal global->LDS for the zero-reuse A stream (CPol NT bit = 2)
__device__ __forceinline__ void gload16nt(const void* g, void* l) {
  __builtin_amdgcn_global_load_lds((const __attribute__((address_space(1))) void*)g,
                                   (__attribute__((address_space(3))) void*)l, 16, 0, 2);
}

// ---------------- kernel 0: W[r][f][u] = sum_k bases[f][u][k] * coef[r][k] ----
__global__ __launch_bounds__(256) void rgcn_wk(const float* __restrict__ bases,
                                               const float* __restrict__ coef,
                                               float* __restrict__ W) {
  int i = blockIdx.x * 256 + threadIdx.x;  // 64*256 = 16384 = R*F*U
  int r = i >> 12;
  int fu = i & 4095;
  float s = 0.f;
#pragma unroll
  for (int k = 0; k < 20; ++k) s += bases[fu * 20 + k] * coef[r * 20 + k];
  W[i] = s;
}

#define PACK8(S, X0, X1)          \
  {                               \
    S[0] = (short)f2bf(X0.x);     \
    S[1] = (short)f2bf(X0.y);     \
    S[2] = (short)f2bf(X0.z);     \
    S[3] = (short)f2bf(X0.w);     \
    S[4] = (short)f2bf(X1.x);     \
    S[5] = (short)f2bf(X1.y);     \
    S[6] = (short)f2bf(X1.z);     \
    S[7] = (short)f2bf(X1.w);     \
  }

// ---------------- kernel 1 (MFMA): xw (bf16, B-fragment layout) + selfout ----
// Wave w computes xw_r = X_tile @ W_w (32x64 @ 64x64) via 16 mfma 16x16x32;
// wave 0 additionally computes selfout = X_tile @ sk + bias.
// xwf layout (unchanged): chunk (r, mb=blk, ut): lane l, elem j holds
//   xw[r][mb*32 + 8*(l>>4) + j][ut*16 + (l&15)] at ((r*256+mb)*4+ut)*512 + l*8 + j
__global__ __launch_bounds__(256) void rgcn_prep(const float* __restrict__ x,
                                                 const float* __restrict__ W,
                                                 const float* __restrict__ sk,
                                                 const float* __restrict__ bias,
                                                 unsigned short* __restrict__ xwf,
                                                 float* __restrict__ selfout) {
  __shared__ float lx[32 * 68];                  // X tile, padded stride 68
  __shared__ unsigned short lxw[4][2048];        // per-wave xw bf16 [32][64]
  const int t = threadIdx.x;
  const int blk = blockIdx.x;
  const int n0 = blk * 32;
  const int w = t >> 6, l = t & 63;
  const int l15 = l & 15, lhi = l >> 4;

  // stage X tile (coalesced, 8 floats/thread)
  {
    const float* xs = x + (size_t)n0 * 64;
    int row = t >> 3, c0 = (t & 7) * 8;
    v4f v0 = *(const v4f*)(xs + row * 64 + c0);
    v4f v1 = *(const v4f*)(xs + row * 64 + c0 + 4);
    *(v4f*)(lx + row * 68 + c0) = v0;
    *(v4f*)(lx + row * 68 + c0 + 4) = v1;
  }
  __syncthreads();

  // A-frags from lx: rf (row group) x c (k chunk)
  v8s af[2][2];
#pragma unroll
  for (int rf = 0; rf < 2; ++rf)
#pragma unroll
    for (int c = 0; c < 2; ++c) {
      const float* p = lx + (rf * 16 + l15) * 68 + c * 32 + 8 * lhi;
      v4f p0 = *(const v4f*)(p);
      v4f p1 = *(const v4f*)(p + 4);
      PACK8(af[rf][c], p0, p1);
    }

  // B-frags from W_w (fp32 global, L2-hot): ut x c, 8 strided scalars each
  const float* wr = W + w * 4096;
  v8s bf[4][2];
#pragma unroll
  for (int ut = 0; ut < 4; ++ut)
#pragma unroll
    for (int c = 0; c < 2; ++c) {
#pragma unroll
      for (int j = 0; j < 8; ++j)
        bf[ut][c][j] = (short)f2bf(wr[(c * 32 + 8 * lhi + j) * 64 + ut * 16 + l15]);
    }

  v4f acc[2][4];
#pragma unroll
  for (int rf = 0; rf < 2; ++rf)
#pragma unroll
    for (int ut = 0; ut < 4; ++ut) acc[rf][ut] = (v4f){0.f, 0.f, 0.f, 0.f};
#pragma unroll
  for (int c = 0; c < 2; ++c)
#pragma unroll
    for (int rf = 0; rf < 2; ++rf)
#pragma unroll
      for (int ut = 0; ut < 4; ++ut)
        acc[rf][ut] = __builtin_amdgcn_mfma_f32_16x16x32_bf16(af[rf][c], bf[ut][c],
                                                              acc[rf][ut], 0, 0, 0);

  // D layout: col = l&15 (u), row = 4*(l>>4)+reg (m within 16-group)
#pragma unroll
  for (int rf = 0; rf < 2; ++rf)
#pragma unroll
    for (int ut = 0; ut < 4; ++ut)
#pragma unroll
      for (int reg = 0; reg < 4; ++reg)
        lxw[w][(rf * 16 + 4 * lhi + reg) * 64 + ut * 16 + l15] = f2bf(acc[rf][ut][reg]);

  asm volatile("s_waitcnt lgkmcnt(0)" ::: "memory");
  __builtin_amdgcn_sched_barrier(0);

  // assemble B-fragment layout and store (16 B contiguous per lane per ut)
#pragma unroll
  for (int ut = 0; ut < 4; ++ut) {
    v8s o;
#pragma unroll
    for (int j = 0; j < 8; ++j)
      o[j] = (short)lxw[w][(8 * lhi + j) * 64 + ut * 16 + l15];
    *(v4u*)(xwf + ((size_t)(w * 256 + blk) * 4 + ut) * 512 + (size_t)l * 8) =
        __builtin_bit_cast(v4u, o);
  }

  // selfout = X @ sk + bias (wave 0 only)
  if (w == 0) {
    v8s sf[4][2];
#pragma unroll
    for (int ut = 0; ut < 4; ++ut)
#pragma unroll
      for (int c = 0; c < 2; ++c) {
#pragma unroll
        for (int j = 0; j < 8; ++j)
          sf[ut][c][j] = (short)f2bf(sk[(c * 32 + 8 * lhi + j) * 64 + ut * 16 + l15]);
      }
    v4f sacc[2][4];
#pragma unroll
    for (int rf = 0; rf < 2; ++rf)
#pragma unroll
      for (int ut = 0; ut < 4; ++ut) sacc[rf][ut] = (v4f){0.f, 0.f, 0.f, 0.f};
#pragma unroll
    for (int c = 0; c < 2; ++c)
#pragma unroll
      for (int rf = 0; rf < 2; ++rf)
#pragma unroll
        for (int ut = 0; ut < 4; ++ut)
          sacc[rf][ut] = __builtin_amdgcn_mfma_f32_16x16x32_bf16(af[rf][c], sf[ut][c],
                                                                 sacc[rf][ut], 0, 0, 0);
#pragma unroll
    for (int rf = 0; rf < 2; ++rf)
#pragma unroll
      for (int ut = 0; ut < 4; ++ut) {
        float bu = bias[ut * 16 + l15];
#pragma unroll
        for (int reg = 0; reg < 4; ++reg)
          selfout[(size_t)(n0 + rf * 16 + 4 * lhi + reg) * 64 + ut * 16 + l15] =
              sacc[rf][ut][reg] + bu;
      }
  }
}

// ---------------- kernel 2: out = relu( sum_r A_r @ xw_r + selfout ) --------
// LDS per (wave w, buf p): 16 KB at smem + w*32768 + p*16384:
//   A tile [32 rows][32 slots of 16B], phys slot = c ^ (row&7) (XOR within
//   8-slot groups). B: no LDS -- double-buffered in VGPRs (sets b0_*, b1_*).

#define STAGE_A(P)                                        \
  {                                                       \
    char* ab = Wb + (P)*16384;                            \
    gload16nt(aps0, ab);                                  \
    gload16nt(aps1, ab + 1024);                           \
    gload16nt(aps2, ab + 2048);                           \
    gload16nt(aps3, ab + 3072);                           \
    gload16nt(aps4, ab + 4096);                           \
    gload16nt(aps5, ab + 5120);                           \
    gload16nt(aps6, ab + 6144);                           \
    gload16nt(aps7, ab + 7168);                           \
    gload16nt(aps8, ab + 8192);                           \
    gload16nt(aps9, ab + 9216);                           \
    gload16nt(aps10, ab + 10240);                         \
    gload16nt(aps11, ab + 11264);                         \
    gload16nt(aps12, ab + 12288);                         \
    gload16nt(aps13, ab + 13312);                         \
    gload16nt(aps14, ab + 14336);                         \
    gload16nt(aps15, ab + 15360);                         \
    aps0 += 128; aps1 += 128; aps2 += 128; aps3 += 128;   \
    aps4 += 128; aps5 += 128; aps6 += 128; aps7 += 128;   \
    aps8 += 128; aps9 += 128; aps10 += 128; aps11 += 128; \
    aps12 += 128; aps13 += 128; aps14 += 128; aps15 += 128; \
  }

#define BLOAD(P)                                    \
  {                                                 \
    b##P##_00 = *(const v4u*)(bsrc);                \
    b##P##_01 = *(const v4u*)(bsrc + 512);          \
    b##P##_02 = *(const v4u*)(bsrc + 1024);         \
    b##P##_03 = *(const v4u*)(bsrc + 1536);         \
    b##P##_10 = *(const v4u*)(bsrc + 2048);         \
    b##P##_11 = *(const v4u*)(bsrc + 2560);         \
    b##P##_12 = *(const v4u*)(bsrc + 3072);         \
    b##P##_13 = *(const v4u*)(bsrc + 3584);         \
    b##P##_20 = *(const v4u*)(bsrc + 4096);         \
    b##P##_21 = *(const v4u*)(bsrc + 4608);         \
    b##P##_22 = *(const v4u*)(bsrc + 5120);         \
    b##P##_23 = *(const v4u*)(bsrc + 5632);         \
    b##P##_30 = *(const v4u*)(bsrc + 6144);         \
    b##P##_31 = *(const v4u*)(bsrc + 6656);         \
    b##P##_32 = *(const v4u*)(bsrc + 7168);         \
    b##P##_33 = *(const v4u*)(bsrc + 7680);         \
    bsrc += 8192;                                   \
  }

#define MFMA8(AF0, AF1, B0, B1, B2, B3)                                          \
  {                                                                              \
    acc00 = __builtin_amdgcn_mfma_f32_16x16x32_bf16(AF0, B0, acc00, 0, 0, 0);    \
    acc01 = __builtin_amdgcn_mfma_f32_16x16x32_bf16(AF0, B1, acc01, 0, 0, 0);    \
    acc02 = __builtin_amdgcn_mfma_f32_16x16x32_bf16(AF0, B2, acc02, 0, 0, 0);    \
    acc03 = __builtin_amdgcn_mfma_f32_16x16x32_bf16(AF0, B3, acc03, 0, 0, 0);    \
    acc10 = __builtin_amdgcn_mfma_f32_16x16x32_bf16(AF1, B0, acc10, 0, 0, 0);    \
    acc11 = __builtin_amdgcn_mfma_f32_16x16x32_bf16(AF1, B1, acc11, 0, 0, 0);    \
    acc12 = __builtin_amdgcn_mfma_f32_16x16x32_bf16(AF1, B2, acc12, 0, 0, 0);    \
    acc13 = __builtin_amdgcn_mfma_f32_16x16x32_bf16(AF1, B3, acc13, 0, 0, 0);    \
  }

#define BC(X) __builtin_bit_cast(v8s, X)

#define STEP(P, VMN, DO_STAGE)                                             \
  {                                                                        \
    asm volatile("s_waitcnt vmcnt(" #VMN ")" ::: "memory");                \
    __builtin_amdgcn_sched_barrier(0);                                     \
    const char* ap = Wb + (P)*16384;                                       \
    v4f a000 = *(const v4f*)(ap + ao000);                                  \
    v4f a001 = *(const v4f*)(ap + ao001);                                  \
    v4f a010 = *(const v4f*)(ap + ao010);                                  \
    v4f a011 = *(const v4f*)(ap + ao011);                                  \
    v4f a100 = *(const v4f*)(ap + ao100);                                  \
    v4f a101 = *(const v4f*)(ap + ao101);                                  \
    v4f a110 = *(const v4f*)(ap + ao110);                                  \
    v4f a111 = *(const v4f*)(ap + ao111);                                  \
    v4f a200 = *(const v4f*)(ap + ao200);                                  \
    v4f a201 = *(const v4f*)(ap + ao201);                                  \
    v4f a210 = *(const v4f*)(ap + ao210);                                  \
    v4f a211 = *(const v4f*)(ap + ao211);                                  \
    v4f a300 = *(const v4f*)(ap + ao300);                                  \
    v4f a301 = *(const v4f*)(ap + ao301);                                  \
    v4f a310 = *(const v4f*)(ap + ao310);                                  \
    v4f a311 = *(const v4f*)(ap + ao311);                                  \
    asm volatile("s_waitcnt lgkmcnt(0)" ::: "memory");                     \
    __builtin_amdgcn_sched_barrier(0);                                     \
    if (DO_STAGE) STAGE_A(P)                                               \
    v8s af0, af1;                                                          \
    PACK8(af0, a000, a001);                                                \
    PACK8(af1, a010, a011);                                                \
    MFMA8(af0, af1, BC(b##P##_00), BC(b##P##_01), BC(b##P##_02), BC(b##P##_03)); \
    PACK8(af0, a100, a101);                                                \
    PACK8(af1, a110, a111);                                                \
    MFMA8(af0, af1, BC(b##P##_10), BC(b##P##_11), BC(b##P##_12), BC(b##P##_13)); \
    PACK8(af0, a200, a201);                                                \
    PACK8(af1, a210, a211);                                                \
    MFMA8(af0, af1, BC(b##P##_20), BC(b##P##_21), BC(b##P##_22), BC(b##P##_23)); \
    PACK8(af0, a300, a301);                                                \
    PACK8(af1, a310, a311);                                                \
    MFMA8(af0, af1, BC(b##P##_30), BC(b##P##_31), BC(b##P##_32), BC(b##P##_33)); \
    if (DO_STAGE) BLOAD(P)                                                 \
  }

#define STORE_FRAG(ACC, RF, UT)                                        \
  red[w][((RF)*16 + lhi * 4 + 0) * 64 + (UT)*16 + l15] = ACC.x;        \
  red[w][((RF)*16 + lhi * 4 + 1) * 64 + (UT)*16 + l15] = ACC.y;        \
  red[w][((RF)*16 + lhi * 4 + 2) * 64 + (UT)*16 + l15] = ACC.z;        \
  red[w][((RF)*16 + lhi * 4 + 3) * 64 + (UT)*16 + l15] = ACC.w;

__global__ __launch_bounds__(256, 1) void rgcn_main(const float* __restrict__ A,
                                                    const unsigned short* __restrict__ xwf,
                                                    float* __restrict__ out) {
  __shared__ __align__(16) char smem[131072];  // 4 waves x 2 bufs x 16KB (A only)
  const int tid = threadIdx.x;
  const int n0 = blockIdx.x * 32;
  const int w = tid >> 6;  // wave = relation
  const int l = tid & 63;
  const int l15 = l & 15, lhi = l >> 4;

  // A staging sources (pre-swizzled): instr J covers tile rows 2J+(l>>5);
  // lane's phys slot l&31 holds logical slot (l&31)^(row&7); LDS dest is
  // linear J*1024 + l*16. Each instr reads 2 x 512 B contiguous segments.
  const float* aps0;  const float* aps1;  const float* aps2;  const float* aps3;
  const float* aps4;  const float* aps5;  const float* aps6;  const float* aps7;
  const float* aps8;  const float* aps9;  const float* aps10; const float* aps11;
  const float* aps12; const float* aps13; const float* aps14; const float* aps15;
  {
    const float* base = A + ((size_t)w * 8192 + (size_t)n0) * 8192;
#define APS_INIT(J, PTR)                                                      \
    {                                                                         \
      int rr = (J)*2 + (l >> 5);                                              \
      int c = (l & 31) ^ (rr & 7);                                            \
      PTR = base + (size_t)rr * 8192 + c * 4;                                 \
    }
    APS_INIT(0, aps0)   APS_INIT(1, aps1)   APS_INIT(2, aps2)   APS_INIT(3, aps3)
    APS_INIT(4, aps4)   APS_INIT(5, aps5)   APS_INIT(6, aps6)   APS_INIT(7, aps7)
    APS_INIT(8, aps8)   APS_INIT(9, aps9)   APS_INIT(10, aps10) APS_INIT(11, aps11)
    APS_INIT(12, aps12) APS_INIT(13, aps13) APS_INIT(14, aps14) APS_INIT(15, aps15)
#undef APS_INIT
  }
  // B source: step t covers xwf shorts [w*524288 + t*8192, +8192)
  const unsigned short* bsrc = xwf + (size_t)w * 524288 + (size_t)l * 8;

  char* Wb = smem + w * 32768;

  // ds_read offsets: k-group g (0..3), frag rf, half h:
  //   row = rf*16 + l15, logical slot c = g*8 + 2*lhi + h, phys = c^(l15&7)
#define AOFF(G, RF, H) ((((RF)*16 + l15) * 32 + (((G)*8 + 2 * lhi + (H)) ^ (l15 & 7))) * 16)
  const int ao000 = AOFF(0, 0, 0), ao001 = AOFF(0, 0, 1);
  const int ao010 = AOFF(0, 1, 0), ao011 = AOFF(0, 1, 1);
  const int ao100 = AOFF(1, 0, 0), ao101 = AOFF(1, 0, 1);
  const int ao110 = AOFF(1, 1, 0), ao111 = AOFF(1, 1, 1);
  const int ao200 = AOFF(2, 0, 0), ao201 = AOFF(2, 0, 1);
  const int ao210 = AOFF(2, 1, 0), ao211 = AOFF(2, 1, 1);
  const int ao300 = AOFF(3, 0, 0), ao301 = AOFF(3, 0, 1);
  const int ao310 = AOFF(3, 1, 0), ao311 = AOFF(3, 1, 1);
#undef AOFF

  // B register double-buffer (2 sets x 16 v4u)
  v4u b0_00, b0_01, b0_02, b0_03, b0_10, b0_11, b0_12, b0_13;
  v4u b0_20, b0_21, b0_22, b0_23, b0_30, b0_31, b0_32, b0_33;
  v4u b1_00, b1_01, b1_02, b1_03, b1_10, b1_11, b1_12, b1_13;
  v4u b1_20, b1_21, b1_22, b1_23, b1_30, b1_31, b1_32, b1_33;

  v4f acc00 = {0.f, 0.f, 0.f, 0.f}, acc01 = {0.f, 0.f, 0.f, 0.f};
  v4f acc02 = {0.f, 0.f, 0.f, 0.f}, acc03 = {0.f, 0.f, 0.f, 0.f};
  v4f acc10 = {0.f, 0.f, 0.f, 0.f}, acc11 = {0.f, 0.f, 0.f, 0.f};
  v4f acc12 = {0.f, 0.f, 0.f, 0.f}, acc13 = {0.f, 0.f, 0.f, 0.f};

  STAGE_A(0) BLOAD(0)  // step 0
  STAGE_A(1) BLOAD(1)  // step 1
  for (int t = 0; t < 31; ++t) {
    STEP(0, 32, 1)  // compute step 2t,   stage step 2t+2
    STEP(1, 32, 1)  // compute step 2t+1, stage step 2t+3
  }
  STEP(0, 32, 0)  // step 62
  STEP(1, 0, 0)   // step 63

  // cross-relation reduction (D layout: col = l&15, row = 4*(l>>4)+reg)
  __syncthreads();
  float(*red)[2048] = (float(*)[2048])smem;
  STORE_FRAG(acc00, 0, 0)
  STORE_FRAG(acc01, 0, 1)
  STORE_FRAG(acc02, 0, 2)
  STORE_FRAG(acc03, 0, 3)
  STORE_FRAG(acc10, 1, 0)
  STORE_FRAG(acc11, 1, 1)
  STORE_FRAG(acc12, 1, 2)
  STORE_FRAG(acc13, 1, 3)
  __syncthreads();
#pragma unroll
  for (int p = 0; p < 8; ++p) {
    int i = tid + 256 * p;
    float v = red[0][i] + red[1][i] + red[2][i] + red[3][i] + out[(size_t)n0 * 64 + i];
    out[(size_t)n0 * 64 + i] = fmaxf(v, 0.f);
  }
}

extern "C" void kernel_launch(void* const* d_in, const int* in_sizes, int n_in,
                              void* d_out, int out_size, void* d_ws, size_t ws_size,
                              hipStream_t stream) {
  const float* feat = (const float*)d_in[0];
  // d_in[1] = out_indices (int64) -- unused (final_layer=False returns all nodes)
  const float* adj = (const float*)d_in[2];
  const float* bases = (const float*)d_in[3];
  const float* coef = (const float*)d_in[4];
  const float* sk = (const float*)d_in[5];
  const float* bias = (const float*)d_in[6];
  float* out = (float*)d_out;

  // ws layout: [0, 4MB) xwf bf16 swizzled; [4MB, 4.25MB) W fp32
  unsigned short* xwf = (unsigned short*)d_ws;
  float* W = (float*)((char*)d_ws + (4u << 20));

  rgcn_wk<<<64, 256, 0, stream>>>(bases, coef, W);
  // selfout is staged in d_out; fully rewritten each call before being read.
  rgcn_prep<<<256, 256, 0, stream>>>(feat, W, sk, bias, xwf, out);
  rgcn_main<<<256, 256, 0, stream>>>(adj, xwf, out);

  (void)in_sizes;
  (void)n_in;
  (void)out_size;
  (void)ws_size;
}